// Round 4
// baseline (155.862 us; speedup 1.0000x reference)
//
#include <hip/hip_runtime.h>
#include <stdint.h>
#include <stddef.h>

// GRIT attention, MI355X bf16-MFMA implementation, round 16.
// = R15 (32K LDS, Q-from-global, counted-vmcnt) with k_flash software-
//   pipelined one tile deep: PV[t-1] + l[t-1] issue from registers at the
//   top of step t (P packed at t-1, V-frags ds_read at t-1, w-frag loaded
//   at t-1), so the matrix pipe gets all 18 MFMAs back-to-back and the
//   exp/pack VALU phase overlaps PV/QK retirement instead of serializing.
//   R13/R14/R15 showed the kernel is neither LDS-BW, vmcnt-drain, nor
//   occupancy bound: time = serialized phase sum (MFMA 38% + VALU 30% +
//   latency gaps). This attacks the serialization itself.

typedef unsigned short u16;
typedef __attribute__((ext_vector_type(8))) short short8;
typedef __attribute__((ext_vector_type(8))) unsigned short us8;
typedef __attribute__((ext_vector_type(4))) unsigned short us4;
typedef __attribute__((ext_vector_type(4))) float floatx4;

__device__ __forceinline__ u16 f2b(float f) {
  union { float f; uint32_t u; } v; v.f = f;
  uint32_t u = v.u;
  return (u16)((u + 0x7fffu + ((u >> 16) & 1u)) >> 16);  // RNE
}

// pack two f32 -> two bf16 (round-half-up): add, add, v_perm
__device__ __forceinline__ uint32_t pkbf16(float a, float b) {
  union { float f; uint32_t u; } x, y; x.f = a; y.f = b;
  return __builtin_amdgcn_perm(y.u + 0x8000u, x.u + 0x8000u, 0x07060302u);
}

#if __has_builtin(__builtin_amdgcn_exp2f)
__device__ __forceinline__ float fexp2(float x) { return __builtin_amdgcn_exp2f(x); }
#else
__device__ __forceinline__ float fexp2(float x) { return exp2f(x); }
#endif

__device__ __forceinline__ void gld16(const u16* g, u16* l) {
  __builtin_amdgcn_global_load_lds(
      (const __attribute__((address_space(1))) uint32_t*)(const void*)g,
      (__attribute__((address_space(3))) uint32_t*)(void*)l, 16, 0, 0);
}

// ---------------- fused prep ----------------

__device__ __forceinline__ void tr_tile(const float* __restrict__ in,
                                        u16* __restrict__ out, int R, int C,
                                        int bx, int by, u16 (*tile)[33]) {
  int tx = threadIdx.x & 31, ty = threadIdx.x >> 5;
  int c0 = bx * 32, r0 = by * 32;
#pragma unroll
  for (int i = 0; i < 32; i += 8)
    tile[ty + i][tx] = f2b(in[(size_t)(r0 + ty + i) * C + c0 + tx]);
  __syncthreads();
#pragma unroll
  for (int i = 0; i < 32; i += 8)
    out[(size_t)(c0 + ty + i) * R + r0 + tx] = tile[tx][ty + i];
}

__global__ __launch_bounds__(256) void k_prep(
    const float* __restrict__ x, u16* __restrict__ xb,
    const float* __restrict__ w_qkv, u16* __restrict__ wqkvT,
    const float* __restrict__ w_out, u16* __restrict__ woutT,
    const float* __restrict__ pe, const float* __restrict__ w_pe,
    const float* __restrict__ b_pe, float* __restrict__ wexp,
    u16* __restrict__ wpb) {
  __shared__ u16 tile[32][33];
  int b = blockIdx.x;
  if (b < 2048) {
    int i = b * 256 + threadIdx.x;
    float4 v = ((const float4*)x)[i];
    uint2 o = make_uint2(pkbf16(v.x, v.y), pkbf16(v.z, v.w));
    ((uint2*)xb)[i] = o;
  } else if (b < 2816) {
    int idx = b - 2048;
    tr_tile(w_qkv, wqkvT, 512, 1536, idx % 48, idx / 48, tile);
  } else if (b < 3072) {
    int idx = b - 2816;
    tr_tile(w_out, woutT, 512, 512, idx % 16, idx / 16, tile);
  } else {
    int idx = (b - 3072) * 256 + threadIdx.x;
    int h = idx >> 12, n = idx & 4095;
    float acc = b_pe[h];
#pragma unroll
    for (int d = 0; d < 16; ++d) acc = fmaf(pe[n * 16 + d], w_pe[d * 8 + h], acc);
    float w = exp2f(acc * 1.4426950408889634f - 16.0f);
    u16 wb = f2b(w);
    union { uint32_t u; float f; } cv; cv.u = ((uint32_t)wb) << 16;
    wexp[h * 4096 + n] = cv.f;  // the SAME bf16-rounded value V' will use
    int pn = (n & ~31) | (((n >> 2) & 3) << 3) | (((n >> 4) & 1) << 2) | (n & 3);
    wpb[h * 4096 + pn] = wb;    // pi-permuted for flash's l B-frag
  }
}

// ---------------- QKV GEMM: 64x128 tile, BK=64, 512 thr, async dbuf ---------
// Q cols (<512) pre-scaled by 0.125*log2e; V cols pre-multiplied by w~ and
// written transposed+pi-permuted to vtp[d][4096] via an LDS transpose buffer
// (coalesced us8 stores instead of 64-lane scattered us4).

__global__ __launch_bounds__(512, 6) void k_gemm_qkv(const u16* __restrict__ A,
                                                     const u16* __restrict__ Bt,
                                                     const float* __restrict__ bias,
                                                     const float* __restrict__ wexp,
                                                     u16* __restrict__ qk,
                                                     u16* __restrict__ vtp) {
  __shared__ __align__(16) u16 smem[24576];  // As 2x4096 @0, Bs 2x8192 @8192
  const int tid = threadIdx.x;
  const int lane = tid & 63, wave = tid >> 6;
  const int colx = lane & 15, quad = lane >> 4;
  const int m0 = blockIdx.y * 64, n0 = blockIdx.x * 128;
  const int wm = wave >> 2, wn = wave & 3;
  const int sc = (lane & 7) ^ ((lane >> 3) & 7);
  const floatx4 fz = {0.f, 0.f, 0.f, 0.f};
  floatx4 acc[2][2];
#pragma unroll
  for (int i = 0; i < 2; ++i)
#pragma unroll
    for (int j = 0; j < 2; ++j) acc[i][j] = fz;

#define PREF_QKV(k0, b)                                                       \
  {                                                                           \
    int rowa = wave * 8 + (lane >> 3);                                        \
    gld16(&A[(size_t)(m0 + rowa) * 512 + (k0) + sc * 8],                      \
          &smem[(b) * 4096 + wave * 512 + lane * 8]);                         \
    _Pragma("unroll") for (int c = 0; c < 2; ++c) {                           \
      int rowb = wave * 16 + c * 8 + (lane >> 3);                             \
      gld16(&Bt[(size_t)(n0 + rowb) * 512 + (k0) + sc * 8],                   \
            &smem[8192 + (b) * 8192 + wave * 1024 + c * 512 + lane * 8]);     \
    }                                                                         \
  }

  PREF_QKV(0, 0);
  __syncthreads();
  for (int it = 0; it < 8; ++it) {
    int cur = it & 1;
    if (it < 7) PREF_QKV((it + 1) * 64, cur ^ 1);
    const u16* As = &smem[cur * 4096];
    const u16* Bs = &smem[8192 + cur * 8192];
#pragma unroll
    for (int kk = 0; kk < 2; ++kk) {
      short8 af[2], bf[2];
#pragma unroll
      for (int i = 0; i < 2; ++i) {
        int row = wm * 32 + i * 16 + colx;
        af[i] = *(const short8*)&As[row * 64 + (((kk * 4 + quad) ^ (colx & 7))) * 8];
      }
#pragma unroll
      for (int j = 0; j < 2; ++j) {
        int row = wn * 32 + j * 16 + colx;
        bf[j] = *(const short8*)&Bs[row * 64 + (((kk * 4 + quad) ^ (colx & 7))) * 8];
      }
#pragma unroll
      for (int i = 0; i < 2; ++i)
#pragma unroll
        for (int j = 0; j < 2; ++j)
          acc[i][j] = __builtin_amdgcn_mfma_f32_16x16x32_bf16(af[i], bf[j], acc[i][j], 0, 0, 0);
    }
    __syncthreads();
  }

  const bool isV = (blockIdx.x >= 8);
  if (!isV) {
#pragma unroll
    for (int j = 0; j < 2; ++j) {
      int c = n0 + wn * 32 + j * 16 + colx;
      float bq = bias[c];
      float qs = (c < 512) ? 0.18033688011112042f : 1.0f;  // 0.125*log2(e)
#pragma unroll
      for (int i = 0; i < 2; ++i)
#pragma unroll
        for (int r = 0; r < 4; ++r) {
          int row = m0 + wm * 32 + i * 16 + quad * 4 + r;
          qk[(size_t)row * 1024 + c] = f2b((acc[i][j][r] + bq) * qs);
        }
    }
  } else {
    // V: w~-fold + transpose + pi through LDS, then coalesced us8 stores.
    const int dv = n0 - 1024;
    u16* Vl = smem;  // [128 d][72] u16 (stride 144B == 16 mod 128: staggered)
    const int hh = (dv + wn * 32) >> 6;  // GLOBAL head; same for j=0,1
#pragma unroll
    for (int j = 0; j < 2; ++j) {
      float bq = bias[n0 + wn * 32 + j * 16 + colx];
#pragma unroll
      for (int i = 0; i < 2; ++i) {
        floatx4 wv = *(const floatx4*)&wexp[hh * 4096 + m0 + wm * 32 + i * 16 + quad * 4];
        us4 o;
#pragma unroll
        for (int r = 0; r < 4; ++r) o[r] = f2b((acc[i][j][r] + bq) * wv[r]);
        int dl = wn * 32 + j * 16 + colx;          // local d 0..127
        int nc = wm * 32 + quad * 8 + i * 4;       // pi-permuted local n
        *(us4*)&Vl[dl * 72 + nc] = o;
      }
    }
    __syncthreads();
#pragma unroll
    for (int t = 0; t < 2; ++t) {
      int idx = t * 512 + tid;
      int dl = idx >> 3, ch = idx & 7;
      *(us8*)&vtp[(size_t)(dv + dl) * 4096 + m0 + ch * 8] =
          *(const us8*)&Vl[dl * 72 + ch * 8];
    }
  }
#undef PREF_QKV
}

// ---------------- flash (fixed-max, linear, KV-split x2, w-folded) ----------
// grid (64 q-tiles, 8 heads, 2 kv-splits), 256 thr = 4 waves = 2 ih x 2 jq,
// 32 q rows per wave. LDS = 32768 B (K dbuf @0, V dbuf @8192 u16 units).
// Software pipeline, one tile deep: at step t the wave issues PV[t-1] and
// l[t-1] MFMAs from registers (pkp / vfr / wfp captured at t-1), then QK[t]
// from LDS; exp/pack[t] overlaps the matrix pipe. Counted vmcnt(5): the 4
// prefetch DMAs + the w-frag load ride across the barrier pair.

__global__ __launch_bounds__(256, 4) void k_flash(const u16* __restrict__ qk,
                                                  const u16* __restrict__ vt,
                                                  const u16* __restrict__ wpb,
                                                  float* __restrict__ opart,
                                                  float* __restrict__ lpart) {
  __shared__ __align__(16) u16 smem[16384];  // 32768 B
  float* bufs = (float*)smem;                // epilogue overlay 2 x 32x65 f32

  const int tid = threadIdx.x;
  const int lane = tid & 63, wave = tid >> 6;
  const int colx = lane & 15, quad = lane >> 4;
  const int ih = wave >> 1, jq = wave & 1;
  const int q0 = blockIdx.x * 64;
  const int h = blockIdx.y;
  const int z = blockIdx.z;
  const int kvb = z * 2048;
  const floatx4 fz = {0.f, 0.f, 0.f, 0.f};

  const int sc = (lane & 7) ^ ((lane >> 3) & 7);
  const int srow = wave * 16 + (lane >> 3);

  // prefetch tile 0: each wave stages 16 K rows and 16 V^T rows (2 gld16 each)
  const u16* qptr = qk + (size_t)(kvb + srow) * 1024 + 512 + h * 64 + sc * 8;
  const u16* vptr = vt + (size_t)(h * 64 + srow) * 4096 + kvb + sc * 8;
  const u16* wptr = wpb + h * 4096 + kvb + jq * 32 + quad * 8;
  gld16(qptr, &smem[wave * 1024 + lane * 8]);
  gld16(qptr + 8192, &smem[wave * 1024 + 512 + lane * 8]);
  gld16(vptr, &smem[8192 + wave * 1024 + lane * 8]);
  gld16(vptr + 32768, &smem[8192 + wave * 1024 + 512 + lane * 8]);
  qptr += 65536;  // 64 kv rows * 1024
  vptr += 64;     // 64 kv cols

  // Q fragments straight from global (no LDS staging; one-time, L2-resident)
  short8 qf[2][2];
#pragma unroll
  for (int iq = 0; iq < 2; ++iq)
#pragma unroll
    for (int kk = 0; kk < 2; ++kk) {
      int row = q0 + ih * 32 + iq * 16 + colx;
      qf[iq][kk] = *(const short8*)&qk[(size_t)row * 1024 + h * 64 + (kk * 4 + quad) * 8];
    }
  __syncthreads();  // drains tile-0 DMA + qf loads (one-time cost)

  floatx4 oacc[2][4], lacc[2];
  lacc[0] = fz; lacc[1] = fz;
#pragma unroll
  for (int iq = 0; iq < 2; ++iq)
#pragma unroll
    for (int cb = 0; cb < 4; ++cb) oacc[iq][cb] = fz;

  // pipeline registers (tile t-1 state)
  union { uint32_t w[4]; short8 s; } pkp[2];
  short8 vfr[4];
  short8 wfp;

#define FBODY(CUR, PREF, DOPV)                                                \
  {                                                                           \
    short8 wfn = *(const short8*)wptr;                                        \
    wptr += 64;                                                               \
    asm volatile("" ::: "memory"); /* wfn load stays before prefetch issue */ \
    if (PREF) {                                                               \
      gld16(qptr, &smem[(1 - (CUR)) * 4096 + wave * 1024 + lane * 8]);        \
      gld16(qptr + 8192,                                                      \
            &smem[(1 - (CUR)) * 4096 + wave * 1024 + 512 + lane * 8]);        \
      gld16(vptr, &smem[8192 + (1 - (CUR)) * 4096 + wave * 1024 + lane * 8]); \
      gld16(vptr + 32768,                                                     \
            &smem[8192 + (1 - (CUR)) * 4096 + wave * 1024 + 512 + lane * 8]); \
      qptr += 65536;                                                          \
      vptr += 64;                                                             \
      /* retire prev tile's 4 DMAs + prev wfn; keep 4 new + this wfn */       \
      asm volatile("s_waitcnt vmcnt(5)" ::: "memory");                        \
    } else {                                                                  \
      asm volatile("s_waitcnt vmcnt(0)" ::: "memory");                        \
    }                                                                         \
    __builtin_amdgcn_s_barrier();                                             \
    asm volatile("" ::: "memory"); /* ds_reads may not hoist above barrier */ \
    const u16* Ks = &smem[(CUR) * 4096];                                      \
    const u16* Vts = &smem[8192 + (CUR) * 4096];                              \
    short8 kf[2][2];                                                          \
    _Pragma("unroll") for (int j2 = 0; j2 < 2; ++j2)                          \
      _Pragma("unroll") for (int kk = 0; kk < 2; ++kk) {                      \
        int row = jq * 32 + j2 * 16 + colx;                                   \
        kf[j2][kk] = *(const short8*)&Ks[row * 64 +                           \
                                         (((kk * 4 + quad) ^ (colx & 7))) * 8]; \
      }                                                                       \
    if (DOPV) { /* PV[t-1] + l[t-1]: pure register operands, no waits */      \
      _Pragma("unroll") for (int cb = 0; cb < 4; ++cb) {                      \
        oacc[0][cb] = __builtin_amdgcn_mfma_f32_16x16x32_bf16(                \
            pkp[0].s, vfr[cb], oacc[0][cb], 0, 0, 0);                         \
        oacc[1][cb] = __builtin_amdgcn_mfma_f32_16x16x32_bf16(                \
            pkp[1].s, vfr[cb], oacc[1][cb], 0, 0, 0);                         \
      }                                                                       \
      lacc[0] = __builtin_amdgcn_mfma_f32_16x16x32_bf16(pkp[0].s, wfp, lacc[0], 0, 0, 0); \
      lacc[1] = __builtin_amdgcn_mfma_f32_16x16x32_bf16(pkp[1].s, wfp, lacc[1], 0, 0, 0); \
    }                                                                         \
    floatx4 sacc[2][2] = {{fz, fz}, {fz, fz}};                                \
    _Pragma("unroll") for (int j2 = 0; j2 < 2; ++j2)                          \
      _Pragma("unroll") for (int kk = 0; kk < 2; ++kk) {                      \
        sacc[0][j2] = __builtin_amdgcn_mfma_f32_16x16x32_bf16(                \
            kf[j2][kk], qf[0][kk], sacc[0][j2], 0, 0, 0);                     \
        sacc[1][j2] = __builtin_amdgcn_mfma_f32_16x16x32_bf16(                \
            kf[j2][kk], qf[1][kk], sacc[1][j2], 0, 0, 0);                     \
      }                                                                       \
    _Pragma("unroll") for (int cb = 0; cb < 4; ++cb) {                        \
      int row = cb * 16 + colx;                                               \
      vfr[cb] = *(const short8*)&Vts[row * 64 +                               \
                                     (((jq * 4 + quad) ^ (colx & 7))) * 8];   \
    }                                                                         \
    _Pragma("unroll") for (int iq = 0; iq < 2; ++iq)                          \
      _Pragma("unroll") for (int j2 = 0; j2 < 2; ++j2) {                      \
        float p0 = fexp2(sacc[iq][j2][0]);                                    \
        float p1 = fexp2(sacc[iq][j2][1]);                                    \
        float p2 = fexp2(sacc[iq][j2][2]);                                    \
        float p3 = fexp2(sacc[iq][j2][3]);                                    \
        pkp[iq].w[j2 * 2 + 0] = pkbf16(p0, p1);                               \
        pkp[iq].w[j2 * 2 + 1] = pkbf16(p2, p3);                               \
      }                                                                       \
    wfp = wfn;                                                                \
    /* all ds_reads retired before anyone can overwrite this buffer */        \
    asm volatile("s_waitcnt lgkmcnt(0)" ::: "memory");                        \
    __builtin_amdgcn_s_barrier();                                             \
    asm volatile("" ::: "memory"); /* next prefetch may not hoist above */    \
  }

  FBODY(0, 1, 0)
  for (int t = 0; t < 15; ++t) {
    FBODY(1, 1, 1)
    FBODY(0, 1, 1)
  }
  FBODY(1, 0, 1)
#undef FBODY

  // drain the pipeline: PV[31] + l[31] from registers
#pragma unroll
  for (int cb = 0; cb < 4; ++cb) {
    oacc[0][cb] = __builtin_amdgcn_mfma_f32_16x16x32_bf16(pkp[0].s, vfr[cb], oacc[0][cb], 0, 0, 0);
    oacc[1][cb] = __builtin_amdgcn_mfma_f32_16x16x32_bf16(pkp[1].s, vfr[cb], oacc[1][cb], 0, 0, 0);
  }
  lacc[0] = __builtin_amdgcn_mfma_f32_16x16x32_bf16(pkp[0].s, wfp, lacc[0], 0, 0, 0);
  lacc[1] = __builtin_amdgcn_mfma_f32_16x16x32_bf16(pkp[1].s, wfp, lacc[1], 0, 0, 0);

  // cross-jq: jq==1 writes O,l to LDS; jq==0 adds and stores partials.
  float* b = bufs + ih * 2080;  // 32 rows x 65 f32 per ih (16640 B total)
  if (jq == 1) {
#pragma unroll
    for (int iq = 0; iq < 2; ++iq)
#pragma unroll
      for (int cb = 0; cb < 4; ++cb)
#pragma unroll
        for (int r = 0; r < 4; ++r)
          b[(iq * 16 + quad * 4 + r) * 65 + cb * 16 + colx] = oacc[iq][cb][r];
    if (colx == 0)
#pragma unroll
      for (int iq = 0; iq < 2; ++iq)
#pragma unroll
        for (int r = 0; r < 4; ++r) b[(iq * 16 + quad * 4 + r) * 65 + 64] = lacc[iq][r];
  }
  __syncthreads();
  if (jq == 0) {
#pragma unroll
    for (int iq = 0; iq < 2; ++iq) {
#pragma unroll
      for (int cb = 0; cb < 4; ++cb)
#pragma unroll
        for (int r = 0; r < 4; ++r)
          oacc[iq][cb][r] += b[(iq * 16 + quad * 4 + r) * 65 + cb * 16 + colx];
#pragma unroll
      for (int r = 0; r < 4; ++r) lacc[iq][r] += b[(iq * 16 + quad * 4 + r) * 65 + 64];
    }
    float* op = opart + (size_t)z * 2097152;
#pragma unroll
    for (int iq = 0; iq < 2; ++iq)
#pragma unroll
      for (int cb = 0; cb < 4; ++cb)
#pragma unroll
        for (int r = 0; r < 4; ++r)
          op[(size_t)(q0 + ih * 32 + iq * 16 + quad * 4 + r) * 512 + h * 64 + cb * 16 + colx] =
              oacc[iq][cb][r];
    if (colx == 0)
#pragma unroll
      for (int iq = 0; iq < 2; ++iq)
#pragma unroll
        for (int r = 0; r < 4; ++r)
          lpart[z * 32768 + h * 4096 + q0 + ih * 32 + iq * 16 + quad * 4 + r] = lacc[iq][r];
  }
}

// ---------------- combine: ao = (O0+O1)/(l0+l1), bf16 ----------------

__global__ __launch_bounds__(256) void k_comb(const float* __restrict__ opart,
                                              const float* __restrict__ lpart,
                                              u16* __restrict__ ao) {
  int idx = blockIdx.x * 256 + threadIdx.x;     // 524288 = 4096 * 128
  int n = idx >> 7, d4 = idx & 127;
  int h = d4 >> 4;
  float l = lpart[h * 4096 + n] + lpart[32768 + h * 4096 + n];
  float inv = 1.0f / l;
  float4 o0 = *(const float4*)&opart[(size_t)n * 512 + d4 * 4];
  float4 o1 = *(const float4*)&opart[2097152 + (size_t)n * 512 + d4 * 4];
  us4 o;
  o[0] = f2b((o0.x + o1.x) * inv);
  o[1] = f2b((o0.y + o1.y) * inv);
  o[2] = f2b((o0.z + o1.z) * inv);
  o[3] = f2b((o0.w + o1.w) * inv);
  *(us4*)&ao[(size_t)n * 512 + d4 * 4] = o;
}

// ---------------- out GEMM: 64x64 tile, BK=64, 512 thr, async dbuf ----------

__global__ __launch_bounds__(512, 4) void k_gemm_out(const u16* __restrict__ A,
                                                     const u16* __restrict__ Bt,
                                                     const float* __restrict__ bias,
                                                     float* __restrict__ Cout) {
  __shared__ __align__(16) u16 smem[16384];  // As 2x4096 @0, Bs 2x4096 @8192
  const int tid = threadIdx.x;
  const int lane = tid & 63, wave = tid >> 6;
  const int colx = lane & 15, quad = lane >> 4;
  const int m0 = blockIdx.y * 64, n0 = blockIdx.x * 64;
  const int wm = wave >> 2, wn = wave & 3;
  const int sc = (lane & 7) ^ ((lane >> 3) & 7);
  const floatx4 fz = {0.f, 0.f, 0.f, 0.f};
  floatx4 acc[2];
  acc[0] = fz; acc[1] = fz;

#define PREF_OUT(k0, b)                                                       \
  {                                                                           \
    int rowa = wave * 8 + (lane >> 3);                                        \
    gld16(&A[(size_t)(m0 + rowa) * 512 + (k0) + sc * 8],                      \
          &smem[(b) * 4096 + wave * 512 + lane * 8]);                         \
    gld16(&Bt[(size_t)(n0 + rowa) * 512 + (k0) + sc * 8],                     \
          &smem[8192 + (b) * 4096 + wave * 512 + lane * 8]);                  \
  }

  PREF_OUT(0, 0);
  __syncthreads();
  for (int it = 0; it < 8; ++it) {
    int cur = it & 1;
    if (it < 7) PREF_OUT((it + 1) * 64, cur ^ 1);
    const u16* As = &smem[cur * 4096];
    const u16* Bs = &smem[8192 + cur * 4096];
#pragma unroll
    for (int kk = 0; kk < 2; ++kk) {
      short8 af[2], bf;
#pragma unroll
      for (int i = 0; i < 2; ++i) {
        int row = wm * 32 + i * 16 + colx;
        af[i] = *(const short8*)&As[row * 64 + (((kk * 4 + quad) ^ (colx & 7))) * 8];
      }
      {
        int row = wn * 16 + colx;
        bf = *(const short8*)&Bs[row * 64 + (((kk * 4 + quad) ^ (colx & 7))) * 8];
      }
#pragma unroll
      for (int i = 0; i < 2; ++i)
        acc[i] = __builtin_amdgcn_mfma_f32_16x16x32_bf16(af[i], bf, acc[i], 0, 0, 0);
    }
    __syncthreads();
  }
  int c = n0 + wn * 16 + colx;
  float bq = bias[c];
#pragma unroll
  for (int i = 0; i < 2; ++i)
#pragma unroll
    for (int r = 0; r < 4; ++r) {
      int row = m0 + wm * 32 + i * 16 + quad * 4 + r;
      Cout[(size_t)row * 512 + c] = acc[i][r] + bq;
    }
#undef PREF_OUT
}

// ---------------- launch ----------------

extern "C" void kernel_launch(void* const* d_in, const int* in_sizes, int n_in,
                              void* d_out, int out_size, void* d_ws, size_t ws_size,
                              hipStream_t stream) {
  const float* x     = (const float*)d_in[0];
  const float* pe    = (const float*)d_in[1];
  const float* w_qkv = (const float*)d_in[2];
  const float* b_qkv = (const float*)d_in[3];
  const float* w_pe  = (const float*)d_in[4];
  const float* b_pe  = (const float*)d_in[5];
  const float* w_out = (const float*)d_in[6];
  const float* b_out = (const float*)d_in[7];
  float* out = (float*)d_out;

  // workspace layout
  u16* xb    = (u16*)d_ws;              // 4096*512
  u16* wqkvT = xb    + 2097152;         // 1536*512
  u16* woutT = wqkvT + 786432;          // 512*512
  u16* qk    = woutT + 262144;          // 4096*1024 (Q'|K)
  u16* vt    = qk    + 4194304;         // 512*4096 (pi-permuted w~-folded V'^T)
  u16* wpb   = vt    + 2097152;         // 8*4096 bf16 (pi-permuted w~)
  u16* ao    = wpb   + 32768;           // 4096*512 bf16
  float* wexp  = (float*)(ao + 2097152); // 8*4096 f32 (same w~, expanded)
  float* opart = wexp + 32768;          // 2 * 4096*512 f32
  float* lpart = opart + 4194304;       // 2 * 8*4096 f32

  k_prep<<<3200, 256, 0, stream>>>(x, xb, w_qkv, wqkvT, w_out, woutT,
                                   pe, w_pe, b_pe, wexp, wpb);
  k_gemm_qkv<<<dim3(12, 64), 512, 0, stream>>>(xb, wqkvT, b_qkv, wexp, qk, vt);
  k_flash<<<dim3(64, 8, 2), 256, 0, stream>>>(qk, vt, wpb, opart, lpart);
  k_comb<<<2048, 256, 0, stream>>>(opart, lpart, ao);
  k_gemm_out<<<dim3(8, 64), 512, 0, stream>>>(ao, woutT, b_out, out);
}

// Round 5
// 148.849 us; speedup vs baseline: 1.0471x; 1.0471x over previous
//
#include <hip/hip_runtime.h>
#include <stdint.h>
#include <stddef.h>

// GRIT attention, MI355X bf16-MFMA implementation, round 17.
// = R15 (32K-era structure, Q-from-global) with k_flash's sync rebuilt:
//   - TRIPLE-buffered K/V (48KB LDS), prefetch distance 1: the DMA issued at
//     step t targets buf (t+1)%3, which no concurrently-executing wave can be
//     reading (slowest wave is in step t-1 reading (t+2)%3) -> the end-of-step
//     barrier is deleted. ONE s_barrier per kv-step (was two).
//   - vmcnt(5) before the barrier: keeps this step's 4 prefetch DMAs + next
//     step's w-frag in flight, retires tile t's DMAs + this step's w-frag.
//   - w-frag register-pipelined one step ahead (wfp/wfn: +4 VGPR only; R16's
//     44-VGPR pipeline state spilled to scratch, +14MB writes, -25% perf).
//   - s_setprio(1) around both MFMA clusters (T5, attn-positive per history).

typedef unsigned short u16;
typedef __attribute__((ext_vector_type(8))) short short8;
typedef __attribute__((ext_vector_type(8))) unsigned short us8;
typedef __attribute__((ext_vector_type(4))) unsigned short us4;
typedef __attribute__((ext_vector_type(4))) float floatx4;

__device__ __forceinline__ u16 f2b(float f) {
  union { float f; uint32_t u; } v; v.f = f;
  uint32_t u = v.u;
  return (u16)((u + 0x7fffu + ((u >> 16) & 1u)) >> 16);  // RNE
}

// pack two f32 -> two bf16 (round-half-up): add, add, v_perm
__device__ __forceinline__ uint32_t pkbf16(float a, float b) {
  union { float f; uint32_t u; } x, y; x.f = a; y.f = b;
  return __builtin_amdgcn_perm(y.u + 0x8000u, x.u + 0x8000u, 0x07060302u);
}

#if __has_builtin(__builtin_amdgcn_exp2f)
__device__ __forceinline__ float fexp2(float x) { return __builtin_amdgcn_exp2f(x); }
#else
__device__ __forceinline__ float fexp2(float x) { return exp2f(x); }
#endif

__device__ __forceinline__ void gld16(const u16* g, u16* l) {
  __builtin_amdgcn_global_load_lds(
      (const __attribute__((address_space(1))) uint32_t*)(const void*)g,
      (__attribute__((address_space(3))) uint32_t*)(void*)l, 16, 0, 0);
}

// ---------------- fused prep ----------------

__device__ __forceinline__ void tr_tile(const float* __restrict__ in,
                                        u16* __restrict__ out, int R, int C,
                                        int bx, int by, u16 (*tile)[33]) {
  int tx = threadIdx.x & 31, ty = threadIdx.x >> 5;
  int c0 = bx * 32, r0 = by * 32;
#pragma unroll
  for (int i = 0; i < 32; i += 8)
    tile[ty + i][tx] = f2b(in[(size_t)(r0 + ty + i) * C + c0 + tx]);
  __syncthreads();
#pragma unroll
  for (int i = 0; i < 32; i += 8)
    out[(size_t)(c0 + ty + i) * R + r0 + tx] = tile[tx][ty + i];
}

__global__ __launch_bounds__(256) void k_prep(
    const float* __restrict__ x, u16* __restrict__ xb,
    const float* __restrict__ w_qkv, u16* __restrict__ wqkvT,
    const float* __restrict__ w_out, u16* __restrict__ woutT,
    const float* __restrict__ pe, const float* __restrict__ w_pe,
    const float* __restrict__ b_pe, float* __restrict__ wexp,
    u16* __restrict__ wpb) {
  __shared__ u16 tile[32][33];
  int b = blockIdx.x;
  if (b < 2048) {
    int i = b * 256 + threadIdx.x;
    float4 v = ((const float4*)x)[i];
    uint2 o = make_uint2(pkbf16(v.x, v.y), pkbf16(v.z, v.w));
    ((uint2*)xb)[i] = o;
  } else if (b < 2816) {
    int idx = b - 2048;
    tr_tile(w_qkv, wqkvT, 512, 1536, idx % 48, idx / 48, tile);
  } else if (b < 3072) {
    int idx = b - 2816;
    tr_tile(w_out, woutT, 512, 512, idx % 16, idx / 16, tile);
  } else {
    int idx = (b - 3072) * 256 + threadIdx.x;
    int h = idx >> 12, n = idx & 4095;
    float acc = b_pe[h];
#pragma unroll
    for (int d = 0; d < 16; ++d) acc = fmaf(pe[n * 16 + d], w_pe[d * 8 + h], acc);
    float w = exp2f(acc * 1.4426950408889634f - 16.0f);
    u16 wb = f2b(w);
    union { uint32_t u; float f; } cv; cv.u = ((uint32_t)wb) << 16;
    wexp[h * 4096 + n] = cv.f;  // the SAME bf16-rounded value V' will use
    int pn = (n & ~31) | (((n >> 2) & 3) << 3) | (((n >> 4) & 1) << 2) | (n & 3);
    wpb[h * 4096 + pn] = wb;    // pi-permuted for flash's l B-frag
  }
}

// ---------------- QKV GEMM: 64x128 tile, BK=64, 512 thr, async dbuf ---------
// Q cols (<512) pre-scaled by 0.125*log2e; V cols pre-multiplied by w~ and
// written transposed+pi-permuted to vtp[d][4096] via an LDS transpose buffer
// (coalesced us8 stores instead of 64-lane scattered us4).

__global__ __launch_bounds__(512, 6) void k_gemm_qkv(const u16* __restrict__ A,
                                                     const u16* __restrict__ Bt,
                                                     const float* __restrict__ bias,
                                                     const float* __restrict__ wexp,
                                                     u16* __restrict__ qk,
                                                     u16* __restrict__ vtp) {
  __shared__ __align__(16) u16 smem[24576];  // As 2x4096 @0, Bs 2x8192 @8192
  const int tid = threadIdx.x;
  const int lane = tid & 63, wave = tid >> 6;
  const int colx = lane & 15, quad = lane >> 4;
  const int m0 = blockIdx.y * 64, n0 = blockIdx.x * 128;
  const int wm = wave >> 2, wn = wave & 3;
  const int sc = (lane & 7) ^ ((lane >> 3) & 7);
  const floatx4 fz = {0.f, 0.f, 0.f, 0.f};
  floatx4 acc[2][2];
#pragma unroll
  for (int i = 0; i < 2; ++i)
#pragma unroll
    for (int j = 0; j < 2; ++j) acc[i][j] = fz;

#define PREF_QKV(k0, b)                                                       \
  {                                                                           \
    int rowa = wave * 8 + (lane >> 3);                                        \
    gld16(&A[(size_t)(m0 + rowa) * 512 + (k0) + sc * 8],                      \
          &smem[(b) * 4096 + wave * 512 + lane * 8]);                         \
    _Pragma("unroll") for (int c = 0; c < 2; ++c) {                           \
      int rowb = wave * 16 + c * 8 + (lane >> 3);                             \
      gld16(&Bt[(size_t)(n0 + rowb) * 512 + (k0) + sc * 8],                   \
            &smem[8192 + (b) * 8192 + wave * 1024 + c * 512 + lane * 8]);     \
    }                                                                         \
  }

  PREF_QKV(0, 0);
  __syncthreads();
  for (int it = 0; it < 8; ++it) {
    int cur = it & 1;
    if (it < 7) PREF_QKV((it + 1) * 64, cur ^ 1);
    const u16* As = &smem[cur * 4096];
    const u16* Bs = &smem[8192 + cur * 8192];
#pragma unroll
    for (int kk = 0; kk < 2; ++kk) {
      short8 af[2], bf[2];
#pragma unroll
      for (int i = 0; i < 2; ++i) {
        int row = wm * 32 + i * 16 + colx;
        af[i] = *(const short8*)&As[row * 64 + (((kk * 4 + quad) ^ (colx & 7))) * 8];
      }
#pragma unroll
      for (int j = 0; j < 2; ++j) {
        int row = wn * 32 + j * 16 + colx;
        bf[j] = *(const short8*)&Bs[row * 64 + (((kk * 4 + quad) ^ (colx & 7))) * 8];
      }
#pragma unroll
      for (int i = 0; i < 2; ++i)
#pragma unroll
        for (int j = 0; j < 2; ++j)
          acc[i][j] = __builtin_amdgcn_mfma_f32_16x16x32_bf16(af[i], bf[j], acc[i][j], 0, 0, 0);
    }
    __syncthreads();
  }

  const bool isV = (blockIdx.x >= 8);
  if (!isV) {
#pragma unroll
    for (int j = 0; j < 2; ++j) {
      int c = n0 + wn * 32 + j * 16 + colx;
      float bq = bias[c];
      float qs = (c < 512) ? 0.18033688011112042f : 1.0f;  // 0.125*log2(e)
#pragma unroll
      for (int i = 0; i < 2; ++i)
#pragma unroll
        for (int r = 0; r < 4; ++r) {
          int row = m0 + wm * 32 + i * 16 + quad * 4 + r;
          qk[(size_t)row * 1024 + c] = f2b((acc[i][j][r] + bq) * qs);
        }
    }
  } else {
    // V: w~-fold + transpose + pi through LDS, then coalesced us8 stores.
    const int dv = n0 - 1024;
    u16* Vl = smem;  // [128 d][72] u16 (stride 144B == 16 mod 128: staggered)
    const int hh = (dv + wn * 32) >> 6;  // GLOBAL head; same for j=0,1
#pragma unroll
    for (int j = 0; j < 2; ++j) {
      float bq = bias[n0 + wn * 32 + j * 16 + colx];
#pragma unroll
      for (int i = 0; i < 2; ++i) {
        floatx4 wv = *(const floatx4*)&wexp[hh * 4096 + m0 + wm * 32 + i * 16 + quad * 4];
        us4 o;
#pragma unroll
        for (int r = 0; r < 4; ++r) o[r] = f2b((acc[i][j][r] + bq) * wv[r]);
        int dl = wn * 32 + j * 16 + colx;          // local d 0..127
        int nc = wm * 32 + quad * 8 + i * 4;       // pi-permuted local n
        *(us4*)&Vl[dl * 72 + nc] = o;
      }
    }
    __syncthreads();
#pragma unroll
    for (int t = 0; t < 2; ++t) {
      int idx = t * 512 + tid;
      int dl = idx >> 3, ch = idx & 7;
      *(us8*)&vtp[(size_t)(dv + dl) * 4096 + m0 + ch * 8] =
          *(const us8*)&Vl[dl * 72 + ch * 8];
    }
  }
#undef PREF_QKV
}

// ---------------- flash (fixed-max, linear, KV-split x2, w-folded) ----------
// grid (64 q-tiles, 8 heads, 2 kv-splits), 256 thr = 4 waves = 2 ih x 2 jq,
// 32 q rows per wave. LDS = 49152 B: K bufs x3 @0, V bufs x3 @24576 B.
// Triple-buffer + prefetch-distance-1 + ONE barrier per step: the DMA issued
// at step t targets buf (t+1)%3; the slowest coexisting wave is in step t-1
// reading buf (t+2)%3 — never the target — so no trailing barrier is needed.
// vmcnt(5) (4 new DMAs + next step's w-frag stay in flight) retires tile t's
// DMAs + this step's w-frag before the rendezvous. setprio(1) around MFMAs.

__global__ __launch_bounds__(256, 4) void k_flash(const u16* __restrict__ qk,
                                                  const u16* __restrict__ vt,
                                                  const u16* __restrict__ wpb,
                                                  float* __restrict__ opart,
                                                  float* __restrict__ lpart) {
  __shared__ __align__(16) u16 smem[24576];  // 49152 B: K 3x4096 u16, V 3x4096
  float* bufs = (float*)smem;                // epilogue overlay 2 x 32x65 f32

  const int tid = threadIdx.x;
  const int lane = tid & 63, wave = tid >> 6;
  const int colx = lane & 15, quad = lane >> 4;
  const int ih = wave >> 1, jq = wave & 1;
  const int q0 = blockIdx.x * 64;
  const int h = blockIdx.y;
  const int z = blockIdx.z;
  const int kvb = z * 2048;
  const floatx4 fz = {0.f, 0.f, 0.f, 0.f};

  const int sc = (lane & 7) ^ ((lane >> 3) & 7);
  const int srow = wave * 16 + (lane >> 3);

  // stage tile 0 into buf 0: each wave 16 K rows + 16 V^T rows (2 gld16 each)
  const u16* qptr = qk + (size_t)(kvb + srow) * 1024 + 512 + h * 64 + sc * 8;
  const u16* vptr = vt + (size_t)(h * 64 + srow) * 4096 + kvb + sc * 8;
  const u16* wptr = wpb + h * 4096 + kvb + jq * 32 + quad * 8;
  gld16(qptr, &smem[wave * 1024 + lane * 8]);
  gld16(qptr + 8192, &smem[wave * 1024 + 512 + lane * 8]);
  gld16(vptr, &smem[12288 + wave * 1024 + lane * 8]);
  gld16(vptr + 32768, &smem[12288 + wave * 1024 + 512 + lane * 8]);
  qptr += 65536;  // 64 kv rows * 1024
  vptr += 64;     // 64 kv cols

  // Q fragments straight from global (no LDS staging; one-time, L2-resident)
  short8 qf[2][2];
#pragma unroll
  for (int iq = 0; iq < 2; ++iq)
#pragma unroll
    for (int kk = 0; kk < 2; ++kk) {
      int row = q0 + ih * 32 + iq * 16 + colx;
      qf[iq][kk] = *(const short8*)&qk[(size_t)row * 1024 + h * 64 + (kk * 4 + quad) * 8];
    }
  // w-frag for step 0 (register pipeline head)
  short8 wfp = *(const short8*)wptr;
  wptr += 64;

  floatx4 oacc[2][4], lacc[2];
  lacc[0] = fz; lacc[1] = fz;
#pragma unroll
  for (int iq = 0; iq < 2; ++iq)
#pragma unroll
    for (int cb = 0; cb < 4; ++cb) oacc[iq][cb] = fz;

  // PB(B): compile-time (B+1)%3 prefetch target
#define PB0 1
#define PB1 2
#define PB2 0
#define FBODY(B, PBX, PREF)                                                   \
  {                                                                           \
    short8 wfn;                                                               \
    if (PREF) {                                                               \
      wfn = *(const short8*)wptr;  /* w-frag for step t+1 */                  \
      wptr += 64;                                                             \
      asm volatile("" ::: "memory");                                          \
      gld16(qptr, &smem[(PBX) * 4096 + wave * 1024 + lane * 8]);              \
      gld16(qptr + 8192,                                                      \
            &smem[(PBX) * 4096 + wave * 1024 + 512 + lane * 8]);              \
      gld16(vptr, &smem[12288 + (PBX) * 4096 + wave * 1024 + lane * 8]);      \
      gld16(vptr + 32768,                                                     \
            &smem[12288 + (PBX) * 4096 + wave * 1024 + 512 + lane * 8]);      \
      qptr += 65536;                                                          \
      vptr += 64;                                                             \
      /* retire tile t's 4 DMAs + this step's wfp; keep 4 new + wfn */        \
      asm volatile("s_waitcnt vmcnt(5)" ::: "memory");                        \
    } else {                                                                  \
      asm volatile("s_waitcnt vmcnt(0)" ::: "memory");                        \
    }                                                                         \
    __builtin_amdgcn_s_barrier();                                             \
    asm volatile("" ::: "memory"); /* ds_reads may not hoist above barrier */ \
    const u16* Ks = &smem[(B) * 4096];                                        \
    const u16* Vts = &smem[12288 + (B) * 4096];                               \
    floatx4 sacc[2][2] = {{fz, fz}, {fz, fz}};                                \
    __builtin_amdgcn_s_setprio(1);                                            \
    _Pragma("unroll") for (int j2 = 0; j2 < 2; ++j2) {                        \
      _Pragma("unroll") for (int kk = 0; kk < 2; ++kk) {                      \
        int row = jq * 32 + j2 * 16 + colx;                                   \
        short8 kf = *(const short8*)&Ks[row * 64 +                            \
                                        (((kk * 4 + quad) ^ (colx & 7))) * 8];\
        sacc[0][j2] = __builtin_amdgcn_mfma_f32_16x16x32_bf16(                \
            kf, qf[0][kk], sacc[0][j2], 0, 0, 0);                             \
        sacc[1][j2] = __builtin_amdgcn_mfma_f32_16x16x32_bf16(                \
            kf, qf[1][kk], sacc[1][j2], 0, 0, 0);                             \
      }                                                                       \
    }                                                                         \
    __builtin_amdgcn_s_setprio(0);                                            \
    union { uint32_t w[4]; short8 s; } pk[2];                                 \
    _Pragma("unroll") for (int iq = 0; iq < 2; ++iq) {                        \
      _Pragma("unroll") for (int j2 = 0; j2 < 2; ++j2) {                      \
        float p0 = fexp2(sacc[iq][j2][0]);                                    \
        float p1 = fexp2(sacc[iq][j2][1]);                                    \
        float p2 = fexp2(sacc[iq][j2][2]);                                    \
        float p3 = fexp2(sacc[iq][j2][3]);                                    \
        pk[iq].w[j2 * 2 + 0] = pkbf16(p0, p1);                                \
        pk[iq].w[j2 * 2 + 1] = pkbf16(p2, p3);                                \
      }                                                                       \
    }                                                                         \
    __builtin_amdgcn_s_setprio(1);                                            \
    _Pragma("unroll") for (int cb = 0; cb < 4; ++cb) {                        \
      int row = cb * 16 + colx;                                               \
      short8 vf = *(const short8*)&Vts[row * 64 +                             \
                                       (((jq * 4 + quad) ^ (colx & 7))) * 8]; \
      oacc[0][cb] = __builtin_amdgcn_mfma_f32_16x16x32_bf16(                  \
          pk[0].s, vf, oacc[0][cb], 0, 0, 0);                                 \
      oacc[1][cb] = __builtin_amdgcn_mfma_f32_16x16x32_bf16(                  \
          pk[1].s, vf, oacc[1][cb], 0, 0, 0);                                 \
    }                                                                         \
    lacc[0] = __builtin_amdgcn_mfma_f32_16x16x32_bf16(pk[0].s, wfp, lacc[0], 0, 0, 0); \
    lacc[1] = __builtin_amdgcn_mfma_f32_16x16x32_bf16(pk[1].s, wfp, lacc[1], 0, 0, 0); \
    __builtin_amdgcn_s_setprio(0);                                            \
    if (PREF) wfp = wfn;                                                      \
    asm volatile("" ::: "memory"); /* no sinking of reads past this point */  \
  }

  FBODY(0, PB0, 1)
  for (int t = 0; t < 10; ++t) {
    FBODY(1, PB1, 1)
    FBODY(2, PB2, 1)
    FBODY(0, PB0, 1)
  }
  FBODY(1, PB1, 0)
#undef FBODY
#undef PB0
#undef PB1
#undef PB2

  __syncthreads();  // all waves' final ds_reads done before overlay writes

  // cross-jq: jq==1 writes O,l to LDS; jq==0 adds and stores partials.
  float* b = bufs + ih * 2080;  // 32 rows x 65 f32 per ih (16640 B total)
  if (jq == 1) {
#pragma unroll
    for (int iq = 0; iq < 2; ++iq)
#pragma unroll
      for (int cb = 0; cb < 4; ++cb)
#pragma unroll
        for (int r = 0; r < 4; ++r)
          b[(iq * 16 + quad * 4 + r) * 65 + cb * 16 + colx] = oacc[iq][cb][r];
    if (colx == 0)
#pragma unroll
      for (int iq = 0; iq < 2; ++iq)
#pragma unroll
        for (int r = 0; r < 4; ++r) b[(iq * 16 + quad * 4 + r) * 65 + 64] = lacc[iq][r];
  }
  __syncthreads();
  if (jq == 0) {
#pragma unroll
    for (int iq = 0; iq < 2; ++iq) {
#pragma unroll
      for (int cb = 0; cb < 4; ++cb)
#pragma unroll
        for (int r = 0; r < 4; ++r)
          oacc[iq][cb][r] += b[(iq * 16 + quad * 4 + r) * 65 + cb * 16 + colx];
#pragma unroll
      for (int r = 0; r < 4; ++r) lacc[iq][r] += b[(iq * 16 + quad * 4 + r) * 65 + 64];
    }
    float* op = opart + (size_t)z * 2097152;
#pragma unroll
    for (int iq = 0; iq < 2; ++iq)
#pragma unroll
      for (int cb = 0; cb < 4; ++cb)
#pragma unroll
        for (int r = 0; r < 4; ++r)
          op[(size_t)(q0 + ih * 32 + iq * 16 + quad * 4 + r) * 512 + h * 64 + cb * 16 + colx] =
              oacc[iq][cb][r];
    if (colx == 0)
#pragma unroll
      for (int iq = 0; iq < 2; ++iq)
#pragma unroll
        for (int r = 0; r < 4; ++r)
          lpart[z * 32768 + h * 4096 + q0 + ih * 32 + iq * 16 + quad * 4 + r] = lacc[iq][r];
  }
}

// ---------------- combine: ao = (O0+O1)/(l0+l1), bf16 ----------------

__global__ __launch_bounds__(256) void k_comb(const float* __restrict__ opart,
                                              const float* __restrict__ lpart,
                                              u16* __restrict__ ao) {
  int idx = blockIdx.x * 256 + threadIdx.x;     // 524288 = 4096 * 128
  int n = idx >> 7, d4 = idx & 127;
  int h = d4 >> 4;
  float l = lpart[h * 4096 + n] + lpart[32768 + h * 4096 + n];
  float inv = 1.0f / l;
  float4 o0 = *(const float4*)&opart[(size_t)n * 512 + d4 * 4];
  float4 o1 = *(const float4*)&opart[2097152 + (size_t)n * 512 + d4 * 4];
  us4 o;
  o[0] = f2b((o0.x + o1.x) * inv);
  o[1] = f2b((o0.y + o1.y) * inv);
  o[2] = f2b((o0.z + o1.z) * inv);
  o[3] = f2b((o0.w + o1.w) * inv);
  *(us4*)&ao[(size_t)n * 512 + d4 * 4] = o;
}

// ---------------- out GEMM: 64x64 tile, BK=64, 512 thr, async dbuf ----------

__global__ __launch_bounds__(512, 4) void k_gemm_out(const u16* __restrict__ A,
                                                     const u16* __restrict__ Bt,
                                                     const float* __restrict__ bias,
                                                     float* __restrict__ Cout) {
  __shared__ __align__(16) u16 smem[16384];  // As 2x4096 @0, Bs 2x4096 @8192
  const int tid = threadIdx.x;
  const int lane = tid & 63, wave = tid >> 6;
  const int colx = lane & 15, quad = lane >> 4;
  const int m0 = blockIdx.y * 64, n0 = blockIdx.x * 64;
  const int wm = wave >> 2, wn = wave & 3;
  const int sc = (lane & 7) ^ ((lane >> 3) & 7);
  const floatx4 fz = {0.f, 0.f, 0.f, 0.f};
  floatx4 acc[2];
  acc[0] = fz; acc[1] = fz;

#define PREF_OUT(k0, b)                                                       \
  {                                                                           \
    int rowa = wave * 8 + (lane >> 3);                                        \
    gld16(&A[(size_t)(m0 + rowa) * 512 + (k0) + sc * 8],                      \
          &smem[(b) * 4096 + wave * 512 + lane * 8]);                         \
    gld16(&Bt[(size_t)(n0 + rowa) * 512 + (k0) + sc * 8],                     \
          &smem[8192 + (b) * 4096 + wave * 512 + lane * 8]);                  \
  }

  PREF_OUT(0, 0);
  __syncthreads();
  for (int it = 0; it < 8; ++it) {
    int cur = it & 1;
    if (it < 7) PREF_OUT((it + 1) * 64, cur ^ 1);
    const u16* As = &smem[cur * 4096];
    const u16* Bs = &smem[8192 + cur * 4096];
#pragma unroll
    for (int kk = 0; kk < 2; ++kk) {
      short8 af[2], bf;
#pragma unroll
      for (int i = 0; i < 2; ++i) {
        int row = wm * 32 + i * 16 + colx;
        af[i] = *(const short8*)&As[row * 64 + (((kk * 4 + quad) ^ (colx & 7))) * 8];
      }
      {
        int row = wn * 16 + colx;
        bf = *(const short8*)&Bs[row * 64 + (((kk * 4 + quad) ^ (colx & 7))) * 8];
      }
#pragma unroll
      for (int i = 0; i < 2; ++i)
        acc[i] = __builtin_amdgcn_mfma_f32_16x16x32_bf16(af[i], bf, acc[i], 0, 0, 0);
    }
    __syncthreads();
  }
  int c = n0 + wn * 16 + colx;
  float bq = bias[c];
#pragma unroll
  for (int i = 0; i < 2; ++i)
#pragma unroll
    for (int r = 0; r < 4; ++r) {
      int row = m0 + wm * 32 + i * 16 + quad * 4 + r;
      Cout[(size_t)row * 512 + c] = acc[i][r] + bq;
    }
#undef PREF_OUT
}

// ---------------- launch ----------------

extern "C" void kernel_launch(void* const* d_in, const int* in_sizes, int n_in,
                              void* d_out, int out_size, void* d_ws, size_t ws_size,
                              hipStream_t stream) {
  const float* x     = (const float*)d_in[0];
  const float* pe    = (const float*)d_in[1];
  const float* w_qkv = (const float*)d_in[2];
  const float* b_qkv = (const float*)d_in[3];
  const float* w_pe  = (const float*)d_in[4];
  const float* b_pe  = (const float*)d_in[5];
  const float* w_out = (const float*)d_in[6];
  const float* b_out = (const float*)d_in[7];
  float* out = (float*)d_out;

  // workspace layout
  u16* xb    = (u16*)d_ws;              // 4096*512
  u16* wqkvT = xb    + 2097152;         // 1536*512
  u16* woutT = wqkvT + 786432;          // 512*512
  u16* qk    = woutT + 262144;          // 4096*1024 (Q'|K)
  u16* vt    = qk    + 4194304;         // 512*4096 (pi-permuted w~-folded V'^T)
  u16* wpb   = vt    + 2097152;         // 8*4096 bf16 (pi-permuted w~)
  u16* ao    = wpb   + 32768;           // 4096*512 bf16
  float* wexp  = (float*)(ao + 2097152); // 8*4096 f32 (same w~, expanded)
  float* opart = wexp + 32768;          // 2 * 4096*512 f32
  float* lpart = opart + 4194304;       // 2 * 8*4096 f32

  k_prep<<<3200, 256, 0, stream>>>(x, xb, w_qkv, wqkvT, w_out, woutT,
                                   pe, w_pe, b_pe, wexp, wpb);
  k_gemm_qkv<<<dim3(12, 64), 512, 0, stream>>>(xb, wqkvT, b_qkv, wexp, qk, vt);
  k_flash<<<dim3(64, 8, 2), 256, 0, stream>>>(qk, vt, wpb, opart, lpart);
  k_comb<<<2048, 256, 0, stream>>>(opart, lpart, ao);
  k_gemm_out<<<dim3(8, 64), 512, 0, stream>>>(ao, woutT, b_out, out);
}

// Round 6
// 137.710 us; speedup vs baseline: 1.1318x; 1.0809x over previous
//
#include <hip/hip_runtime.h>
#include <stdint.h>
#include <stddef.h>

// GRIT attention, MI355X bf16-MFMA implementation, round 18.
// k_flash: exact revert to R13's structure (best measured: 46.4 us —
//   4 waves x 32q, Q staged via LDS, plain __syncthreads dbuf, 40960 B LDS)
//   with the KV-split removed: grid (64,8), 64 kv-steps per block.
// Pipeline consolidation: k_comb is DELETED — normalization (O/l -> bf16)
//   fused into k_flash's epilogue. 4 launches instead of 5. Removes the
//   opart/lpart f32 round-trip (~40 MB of HBM traffic) and one serial
//   inter-kernel gap.
// R13-R17 lesson: k_flash is invariant ~47 us across occupancy 21-61%, LDS
//   traffic 2x, barrier structure — its wall is unexplained, so this round
//   stops micro-opting it and shrinks everything around it.

typedef unsigned short u16;
typedef __attribute__((ext_vector_type(8))) short short8;
typedef __attribute__((ext_vector_type(8))) unsigned short us8;
typedef __attribute__((ext_vector_type(4))) unsigned short us4;
typedef __attribute__((ext_vector_type(4))) float floatx4;

__device__ __forceinline__ u16 f2b(float f) {
  union { float f; uint32_t u; } v; v.f = f;
  uint32_t u = v.u;
  return (u16)((u + 0x7fffu + ((u >> 16) & 1u)) >> 16);  // RNE
}

// pack two f32 -> two bf16 (round-half-up): add, add, v_perm
__device__ __forceinline__ uint32_t pkbf16(float a, float b) {
  union { float f; uint32_t u; } x, y; x.f = a; y.f = b;
  return __builtin_amdgcn_perm(y.u + 0x8000u, x.u + 0x8000u, 0x07060302u);
}

#if __has_builtin(__builtin_amdgcn_exp2f)
__device__ __forceinline__ float fexp2(float x) { return __builtin_amdgcn_exp2f(x); }
#else
__device__ __forceinline__ float fexp2(float x) { return exp2f(x); }
#endif

__device__ __forceinline__ void gld16(const u16* g, u16* l) {
  __builtin_amdgcn_global_load_lds(
      (const __attribute__((address_space(1))) uint32_t*)(const void*)g,
      (__attribute__((address_space(3))) uint32_t*)(void*)l, 16, 0, 0);
}

// ---------------- fused prep ----------------

__device__ __forceinline__ void tr_tile(const float* __restrict__ in,
                                        u16* __restrict__ out, int R, int C,
                                        int bx, int by, u16 (*tile)[33]) {
  int tx = threadIdx.x & 31, ty = threadIdx.x >> 5;
  int c0 = bx * 32, r0 = by * 32;
#pragma unroll
  for (int i = 0; i < 32; i += 8)
    tile[ty + i][tx] = f2b(in[(size_t)(r0 + ty + i) * C + c0 + tx]);
  __syncthreads();
#pragma unroll
  for (int i = 0; i < 32; i += 8)
    out[(size_t)(c0 + ty + i) * R + r0 + tx] = tile[tx][ty + i];
}

__global__ __launch_bounds__(256) void k_prep(
    const float* __restrict__ x, u16* __restrict__ xb,
    const float* __restrict__ w_qkv, u16* __restrict__ wqkvT,
    const float* __restrict__ w_out, u16* __restrict__ woutT,
    const float* __restrict__ pe, const float* __restrict__ w_pe,
    const float* __restrict__ b_pe, float* __restrict__ wexp,
    u16* __restrict__ wpb) {
  __shared__ u16 tile[32][33];
  int b = blockIdx.x;
  if (b < 2048) {
    int i = b * 256 + threadIdx.x;
    float4 v = ((const float4*)x)[i];
    uint2 o = make_uint2(pkbf16(v.x, v.y), pkbf16(v.z, v.w));
    ((uint2*)xb)[i] = o;
  } else if (b < 2816) {
    int idx = b - 2048;
    tr_tile(w_qkv, wqkvT, 512, 1536, idx % 48, idx / 48, tile);
  } else if (b < 3072) {
    int idx = b - 2816;
    tr_tile(w_out, woutT, 512, 512, idx % 16, idx / 16, tile);
  } else {
    int idx = (b - 3072) * 256 + threadIdx.x;
    int h = idx >> 12, n = idx & 4095;
    float acc = b_pe[h];
#pragma unroll
    for (int d = 0; d < 16; ++d) acc = fmaf(pe[n * 16 + d], w_pe[d * 8 + h], acc);
    float w = exp2f(acc * 1.4426950408889634f - 16.0f);
    u16 wb = f2b(w);
    union { uint32_t u; float f; } cv; cv.u = ((uint32_t)wb) << 16;
    wexp[h * 4096 + n] = cv.f;  // the SAME bf16-rounded value V' will use
    int pn = (n & ~31) | (((n >> 2) & 3) << 3) | (((n >> 4) & 1) << 2) | (n & 3);
    wpb[h * 4096 + pn] = wb;    // pi-permuted for flash's l B-frag
  }
}

// ---------------- QKV GEMM: 64x128 tile, BK=64, 512 thr, async dbuf ---------
// Q cols (<512) pre-scaled by 0.125*log2e; V cols pre-multiplied by w~ and
// written transposed+pi-permuted to vtp[d][4096] via an LDS transpose buffer
// (coalesced us8 stores instead of 64-lane scattered us4).

__global__ __launch_bounds__(512, 6) void k_gemm_qkv(const u16* __restrict__ A,
                                                     const u16* __restrict__ Bt,
                                                     const float* __restrict__ bias,
                                                     const float* __restrict__ wexp,
                                                     u16* __restrict__ qk,
                                                     u16* __restrict__ vtp) {
  __shared__ __align__(16) u16 smem[24576];  // As 2x4096 @0, Bs 2x8192 @8192
  const int tid = threadIdx.x;
  const int lane = tid & 63, wave = tid >> 6;
  const int colx = lane & 15, quad = lane >> 4;
  const int m0 = blockIdx.y * 64, n0 = blockIdx.x * 128;
  const int wm = wave >> 2, wn = wave & 3;
  const int sc = (lane & 7) ^ ((lane >> 3) & 7);
  const floatx4 fz = {0.f, 0.f, 0.f, 0.f};
  floatx4 acc[2][2];
#pragma unroll
  for (int i = 0; i < 2; ++i)
#pragma unroll
    for (int j = 0; j < 2; ++j) acc[i][j] = fz;

#define PREF_QKV(k0, b)                                                       \
  {                                                                           \
    int rowa = wave * 8 + (lane >> 3);                                        \
    gld16(&A[(size_t)(m0 + rowa) * 512 + (k0) + sc * 8],                      \
          &smem[(b) * 4096 + wave * 512 + lane * 8]);                         \
    _Pragma("unroll") for (int c = 0; c < 2; ++c) {                           \
      int rowb = wave * 16 + c * 8 + (lane >> 3);                             \
      gld16(&Bt[(size_t)(n0 + rowb) * 512 + (k0) + sc * 8],                   \
            &smem[8192 + (b) * 8192 + wave * 1024 + c * 512 + lane * 8]);     \
    }                                                                         \
  }

  PREF_QKV(0, 0);
  __syncthreads();
  for (int it = 0; it < 8; ++it) {
    int cur = it & 1;
    if (it < 7) PREF_QKV((it + 1) * 64, cur ^ 1);
    const u16* As = &smem[cur * 4096];
    const u16* Bs = &smem[8192 + cur * 8192];
#pragma unroll
    for (int kk = 0; kk < 2; ++kk) {
      short8 af[2], bf[2];
#pragma unroll
      for (int i = 0; i < 2; ++i) {
        int row = wm * 32 + i * 16 + colx;
        af[i] = *(const short8*)&As[row * 64 + (((kk * 4 + quad) ^ (colx & 7))) * 8];
      }
#pragma unroll
      for (int j = 0; j < 2; ++j) {
        int row = wn * 32 + j * 16 + colx;
        bf[j] = *(const short8*)&Bs[row * 64 + (((kk * 4 + quad) ^ (colx & 7))) * 8];
      }
#pragma unroll
      for (int i = 0; i < 2; ++i)
#pragma unroll
        for (int j = 0; j < 2; ++j)
          acc[i][j] = __builtin_amdgcn_mfma_f32_16x16x32_bf16(af[i], bf[j], acc[i][j], 0, 0, 0);
    }
    __syncthreads();
  }

  const bool isV = (blockIdx.x >= 8);
  if (!isV) {
#pragma unroll
    for (int j = 0; j < 2; ++j) {
      int c = n0 + wn * 32 + j * 16 + colx;
      float bq = bias[c];
      float qs = (c < 512) ? 0.18033688011112042f : 1.0f;  // 0.125*log2(e)
#pragma unroll
      for (int i = 0; i < 2; ++i)
#pragma unroll
        for (int r = 0; r < 4; ++r) {
          int row = m0 + wm * 32 + i * 16 + quad * 4 + r;
          qk[(size_t)row * 1024 + c] = f2b((acc[i][j][r] + bq) * qs);
        }
    }
  } else {
    // V: w~-fold + transpose + pi through LDS, then coalesced us8 stores.
    const int dv = n0 - 1024;
    u16* Vl = smem;  // [128 d][72] u16 (stride 144B == 16 mod 128: staggered)
    const int hh = (dv + wn * 32) >> 6;  // GLOBAL head; same for j=0,1
#pragma unroll
    for (int j = 0; j < 2; ++j) {
      float bq = bias[n0 + wn * 32 + j * 16 + colx];
#pragma unroll
      for (int i = 0; i < 2; ++i) {
        floatx4 wv = *(const floatx4*)&wexp[hh * 4096 + m0 + wm * 32 + i * 16 + quad * 4];
        us4 o;
#pragma unroll
        for (int r = 0; r < 4; ++r) o[r] = f2b((acc[i][j][r] + bq) * wv[r]);
        int dl = wn * 32 + j * 16 + colx;          // local d 0..127
        int nc = wm * 32 + quad * 8 + i * 4;       // pi-permuted local n
        *(us4*)&Vl[dl * 72 + nc] = o;
      }
    }
    __syncthreads();
#pragma unroll
    for (int t = 0; t < 2; ++t) {
      int idx = t * 512 + tid;
      int dl = idx >> 3, ch = idx & 7;
      *(us8*)&vtp[(size_t)(dv + dl) * 4096 + m0 + ch * 8] =
          *(const us8*)&Vl[dl * 72 + ch * 8];
    }
  }
#undef PREF_QKV
}

// ---------------- flash (fixed-max, linear, NO kv-split, w-folded) ----------
// grid (64 q-tiles, 8 heads), 256 thr = 4 waves = 2 ih x 2 jq, 32 q rows per
// wave, 64 kv-steps of 64. R13 structure verbatim: Q staged via LDS, plain
// __syncthreads double-buffer, LDS 40960 B. Epilogue normalizes (O * 1/l)
// and writes bf16 ao directly (k_comb fused away).

__global__ __launch_bounds__(256, 4) void k_flash(const u16* __restrict__ qk,
                                                  const u16* __restrict__ vt,
                                                  const u16* __restrict__ wpb,
                                                  u16* __restrict__ ao) {
  __shared__ __align__(16) u16 smem[20480];  // 40960 B
  float* bufs = (float*)smem;                // epilogue overlay 2 x 32x65 f32

  const int tid = threadIdx.x;
  const int lane = tid & 63, wave = tid >> 6;
  const int colx = lane & 15, quad = lane >> 4;
  const int ih = wave >> 1, jq = wave & 1;
  const int q0 = blockIdx.x * 64;
  const int h = blockIdx.y;
  const floatx4 fz = {0.f, 0.f, 0.f, 0.f};

  const int sc = (lane & 7) ^ ((lane >> 3) & 7);
  const int srow = wave * 16 + (lane >> 3);

  // stage Q (swizzled ds_write): 64 rows x 64 cols, 2 passes of 256 thr
#pragma unroll
  for (int t = 0; t < 2; ++t) {
    int idx = t * 256 + tid;
    int row = idx >> 3, ch = idx & 7;
    *(us8*)&smem[row * 64 + (ch ^ (row & 7)) * 8] =
        *(const us8*)&qk[(size_t)(q0 + row) * 1024 + h * 64 + ch * 8];
  }
  // prefetch tile 0: each wave stages 16 K rows and 16 V^T rows (2 gld16 each)
  const u16* qptr = qk + (size_t)srow * 1024 + 512 + h * 64 + sc * 8;
  const u16* vptr = vt + (size_t)(h * 64 + srow) * 4096 + sc * 8;
  const u16* wptr = wpb + h * 4096 + jq * 32 + quad * 8;
  gld16(qptr, &smem[4096 + wave * 1024 + lane * 8]);
  gld16(qptr + 8192, &smem[4096 + wave * 1024 + 512 + lane * 8]);
  gld16(vptr, &smem[12288 + wave * 1024 + lane * 8]);
  gld16(vptr + 32768, &smem[12288 + wave * 1024 + 512 + lane * 8]);
  qptr += 65536;  // 64 kv rows * 1024
  vptr += 64;     // 64 kv cols
  __syncthreads();

  short8 qf[2][2];
#pragma unroll
  for (int iq = 0; iq < 2; ++iq)
#pragma unroll
    for (int kk = 0; kk < 2; ++kk) {
      int row = ih * 32 + iq * 16 + colx;
      qf[iq][kk] = *(const short8*)&smem[row * 64 + (((kk * 4 + quad) ^ (colx & 7))) * 8];
    }

  floatx4 oacc[2][4], lacc[2];
  lacc[0] = fz; lacc[1] = fz;
#pragma unroll
  for (int iq = 0; iq < 2; ++iq)
#pragma unroll
    for (int cb = 0; cb < 4; ++cb) oacc[iq][cb] = fz;

#define FBODY(CUR, PREF)                                                      \
  {                                                                           \
    short8 wf = *(const short8*)wptr;                                         \
    wptr += 64;                                                               \
    if (PREF) {                                                               \
      gld16(qptr, &smem[4096 + (1 - (CUR)) * 4096 + wave * 1024 + lane * 8]); \
      gld16(qptr + 8192,                                                      \
            &smem[4096 + (1 - (CUR)) * 4096 + wave * 1024 + 512 + lane * 8]); \
      gld16(vptr, &smem[12288 + (1 - (CUR)) * 4096 + wave * 1024 + lane * 8]);\
      gld16(vptr + 32768,                                                     \
            &smem[12288 + (1 - (CUR)) * 4096 + wave * 1024 + 512 + lane * 8]);\
      qptr += 65536;                                                          \
      vptr += 64;                                                             \
    }                                                                         \
    const u16* Ks = &smem[4096 + (CUR) * 4096];                               \
    const u16* Vts = &smem[12288 + (CUR) * 4096];                             \
    floatx4 sacc[2][2] = {{fz, fz}, {fz, fz}};                                \
    _Pragma("unroll") for (int j2 = 0; j2 < 2; ++j2) {                        \
      _Pragma("unroll") for (int kk = 0; kk < 2; ++kk) {                      \
        int row = jq * 32 + j2 * 16 + colx;                                   \
        short8 kf = *(const short8*)&Ks[row * 64 +                            \
                                        (((kk * 4 + quad) ^ (colx & 7))) * 8];\
        sacc[0][j2] = __builtin_amdgcn_mfma_f32_16x16x32_bf16(                \
            kf, qf[0][kk], sacc[0][j2], 0, 0, 0);                             \
        sacc[1][j2] = __builtin_amdgcn_mfma_f32_16x16x32_bf16(                \
            kf, qf[1][kk], sacc[1][j2], 0, 0, 0);                             \
      }                                                                       \
    }                                                                         \
    union { uint32_t w[4]; short8 s; } pk[2];                                 \
    _Pragma("unroll") for (int iq = 0; iq < 2; ++iq) {                        \
      _Pragma("unroll") for (int j2 = 0; j2 < 2; ++j2) {                      \
        float p0 = fexp2(sacc[iq][j2][0]);                                    \
        float p1 = fexp2(sacc[iq][j2][1]);                                    \
        float p2 = fexp2(sacc[iq][j2][2]);                                    \
        float p3 = fexp2(sacc[iq][j2][3]);                                    \
        pk[iq].w[j2 * 2 + 0] = pkbf16(p0, p1);                                \
        pk[iq].w[j2 * 2 + 1] = pkbf16(p2, p3);                                \
      }                                                                       \
    }                                                                         \
    _Pragma("unroll") for (int cb = 0; cb < 4; ++cb) {                        \
      int row = cb * 16 + colx;                                               \
      short8 vf = *(const short8*)&Vts[row * 64 +                             \
                                       (((jq * 4 + quad) ^ (colx & 7))) * 8]; \
      oacc[0][cb] = __builtin_amdgcn_mfma_f32_16x16x32_bf16(                  \
          pk[0].s, vf, oacc[0][cb], 0, 0, 0);                                 \
      oacc[1][cb] = __builtin_amdgcn_mfma_f32_16x16x32_bf16(                  \
          pk[1].s, vf, oacc[1][cb], 0, 0, 0);                                 \
    }                                                                         \
    lacc[0] = __builtin_amdgcn_mfma_f32_16x16x32_bf16(pk[0].s, wf, lacc[0], 0, 0, 0); \
    lacc[1] = __builtin_amdgcn_mfma_f32_16x16x32_bf16(pk[1].s, wf, lacc[1], 0, 0, 0); \
    __syncthreads();                                                          \
  }

  for (int t = 0; t < 31; ++t) {
    FBODY(0, 1)
    FBODY(1, 1)
  }
  FBODY(0, 1)
  FBODY(1, 0)
#undef FBODY

  // cross-jq: jq==1 writes O,l to LDS; jq==0 adds, normalizes, stores bf16.
  float* b = bufs + ih * 2080;  // 32 rows x 65 f32 per ih (16640 B total)
  if (jq == 1) {
#pragma unroll
    for (int iq = 0; iq < 2; ++iq)
#pragma unroll
      for (int cb = 0; cb < 4; ++cb)
#pragma unroll
        for (int r = 0; r < 4; ++r)
          b[(iq * 16 + quad * 4 + r) * 65 + cb * 16 + colx] = oacc[iq][cb][r];
    if (colx == 0)
#pragma unroll
      for (int iq = 0; iq < 2; ++iq)
#pragma unroll
        for (int r = 0; r < 4; ++r) b[(iq * 16 + quad * 4 + r) * 65 + 64] = lacc[iq][r];
  }
  __syncthreads();
  if (jq == 0) {
#pragma unroll
    for (int iq = 0; iq < 2; ++iq) {
#pragma unroll
      for (int cb = 0; cb < 4; ++cb)
#pragma unroll
        for (int r = 0; r < 4; ++r)
          oacc[iq][cb][r] += b[(iq * 16 + quad * 4 + r) * 65 + cb * 16 + colx];
#pragma unroll
      for (int r = 0; r < 4; ++r) lacc[iq][r] += b[(iq * 16 + quad * 4 + r) * 65 + 64];
    }
#pragma unroll
    for (int iq = 0; iq < 2; ++iq) {
      float inv[4];
#pragma unroll
      for (int r = 0; r < 4; ++r) inv[r] = 1.0f / lacc[iq][r];
#pragma unroll
      for (int cb = 0; cb < 4; ++cb)
#pragma unroll
        for (int r = 0; r < 4; ++r) {
          int row = q0 + ih * 32 + iq * 16 + quad * 4 + r;
          ao[(size_t)row * 512 + h * 64 + cb * 16 + colx] =
              f2b(oacc[iq][cb][r] * inv[r]);
        }
    }
  }
}

// ---------------- out GEMM: 64x64 tile, BK=64, 512 thr, async dbuf ----------

__global__ __launch_bounds__(512, 4) void k_gemm_out(const u16* __restrict__ A,
                                                     const u16* __restrict__ Bt,
                                                     const float* __restrict__ bias,
                                                     float* __restrict__ Cout) {
  __shared__ __align__(16) u16 smem[16384];  // As 2x4096 @0, Bs 2x4096 @8192
  const int tid = threadIdx.x;
  const int lane = tid & 63, wave = tid >> 6;
  const int colx = lane & 15, quad = lane >> 4;
  const int m0 = blockIdx.y * 64, n0 = blockIdx.x * 64;
  const int wm = wave >> 2, wn = wave & 3;
  const int sc = (lane & 7) ^ ((lane >> 3) & 7);
  const floatx4 fz = {0.f, 0.f, 0.f, 0.f};
  floatx4 acc[2];
  acc[0] = fz; acc[1] = fz;

#define PREF_OUT(k0, b)                                                       \
  {                                                                           \
    int rowa = wave * 8 + (lane >> 3);                                        \
    gld16(&A[(size_t)(m0 + rowa) * 512 + (k0) + sc * 8],                      \
          &smem[(b) * 4096 + wave * 512 + lane * 8]);                         \
    gld16(&Bt[(size_t)(n0 + rowa) * 512 + (k0) + sc * 8],                     \
          &smem[8192 + (b) * 4096 + wave * 512 + lane * 8]);                  \
  }

  PREF_OUT(0, 0);
  __syncthreads();
  for (int it = 0; it < 8; ++it) {
    int cur = it & 1;
    if (it < 7) PREF_OUT((it + 1) * 64, cur ^ 1);
    const u16* As = &smem[cur * 4096];
    const u16* Bs = &smem[8192 + cur * 4096];
#pragma unroll
    for (int kk = 0; kk < 2; ++kk) {
      short8 af[2], bf;
#pragma unroll
      for (int i = 0; i < 2; ++i) {
        int row = wm * 32 + i * 16 + colx;
        af[i] = *(const short8*)&As[row * 64 + (((kk * 4 + quad) ^ (colx & 7))) * 8];
      }
      {
        int row = wn * 16 + colx;
        bf = *(const short8*)&Bs[row * 64 + (((kk * 4 + quad) ^ (colx & 7))) * 8];
      }
#pragma unroll
      for (int i = 0; i < 2; ++i)
        acc[i] = __builtin_amdgcn_mfma_f32_16x16x32_bf16(af[i], bf, acc[i], 0, 0, 0);
    }
    __syncthreads();
  }
  int c = n0 + wn * 16 + colx;
  float bq = bias[c];
#pragma unroll
  for (int i = 0; i < 2; ++i)
#pragma unroll
    for (int r = 0; r < 4; ++r) {
      int row = m0 + wm * 32 + i * 16 + quad * 4 + r;
      Cout[(size_t)row * 512 + c] = acc[i][r] + bq;
    }
#undef PREF_OUT
}

// ---------------- launch ----------------

extern "C" void kernel_launch(void* const* d_in, const int* in_sizes, int n_in,
                              void* d_out, int out_size, void* d_ws, size_t ws_size,
                              hipStream_t stream) {
  const float* x     = (const float*)d_in[0];
  const float* pe    = (const float*)d_in[1];
  const float* w_qkv = (const float*)d_in[2];
  const float* b_qkv = (const float*)d_in[3];
  const float* w_pe  = (const float*)d_in[4];
  const float* b_pe  = (const float*)d_in[5];
  const float* w_out = (const float*)d_in[6];
  const float* b_out = (const float*)d_in[7];
  float* out = (float*)d_out;

  // workspace layout
  u16* xb    = (u16*)d_ws;              // 4096*512
  u16* wqkvT = xb    + 2097152;         // 1536*512
  u16* woutT = wqkvT + 786432;          // 512*512
  u16* qk    = woutT + 262144;          // 4096*1024 (Q'|K)
  u16* vt    = qk    + 4194304;         // 512*4096 (pi-permuted w~-folded V'^T)
  u16* wpb   = vt    + 2097152;         // 8*4096 bf16 (pi-permuted w~)
  u16* ao    = wpb   + 32768;           // 4096*512 bf16
  float* wexp  = (float*)(ao + 2097152); // 8*4096 f32 (same w~, expanded)

  k_prep<<<3200, 256, 0, stream>>>(x, xb, w_qkv, wqkvT, w_out, woutT,
                                   pe, w_pe, b_pe, wexp, wpb);
  k_gemm_qkv<<<dim3(12, 64), 512, 0, stream>>>(xb, wqkvT, b_qkv, wexp, qk, vt);
  k_flash<<<dim3(64, 8), 256, 0, stream>>>(qk, vt, wpb, ao);
  k_gemm_out<<<dim3(8, 64), 512, 0, stream>>>(ao, woutT, b_out, out);
}